// Round 3
// baseline (1973.957 us; speedup 1.0000x reference)
//
#include <hip/hip_runtime.h>
#include <hip/hip_bf16.h>

#define BB 32
#define NN 2048
#define MM 512
#define DD 512
#define TS 64
#define KC 16
#define PAD 4  // LDS row stride 68 floats: 16B-aligned rows, breaks 64-stride bank conflicts

__device__ __forceinline__ float bf2f(unsigned short u) {
    union { unsigned int i; float f; } v; v.i = ((unsigned int)u) << 16; return v.f;
}
__device__ __forceinline__ unsigned short f2bf(float f) {
    union { float f; unsigned int i; } v; v.f = f;
    unsigned int x = v.i;
    return (unsigned short)((x + 0x7FFFu + ((x >> 16) & 1u)) >> 16);
}

// K1: c1[b,n] = C[b,n,:]·w1 ; q2[b,m] = Q[b,m,:]·w2. One wave per row, 4 waves/block.
__global__ __launch_bounds__(256) void k_dots(const float* __restrict__ C, const float* __restrict__ Q,
                                              const float* __restrict__ w,
                                              float* __restrict__ c1, float* __restrict__ q2) {
    int wid  = blockIdx.x * 4 + (threadIdx.x >> 6);
    int lane = threadIdx.x & 63;
    const int NR1 = BB * NN;
    const float* src; const float* wv; float* dst;
    if (wid < NR1) { src = C + (size_t)wid * DD; wv = w;       dst = c1 + wid; }
    else { int r = wid - NR1; src = Q + (size_t)r * DD; wv = w + DD; dst = q2 + r; }
    float4 a0 = *(const float4*)(src + lane * 8);
    float4 a1 = *(const float4*)(src + lane * 8 + 4);
    float4 b0 = *(const float4*)(wv  + lane * 8);
    float4 b1 = *(const float4*)(wv  + lane * 8 + 4);
    float s = a0.x * b0.x + a0.y * b0.y + a0.z * b0.z + a0.w * b0.w
            + a1.x * b1.x + a1.y * b1.y + a1.z * b1.z + a1.w * b1.w;
#pragma unroll
    for (int o = 32; o > 0; o >>= 1) s += __shfl_down(s, o);
    if (lane == 0) *dst = s;
}

// K2: E[b,n,m] = bf16(exp(c1 + q2 + (C*w3)·Q)); masked row/col sums of the QUANTIZED exp
// accumulated to rsum/csum (fp32) via LDS + global atomics.
__global__ __launch_bounds__(256) void k_sgemm(const float* __restrict__ C, const float* __restrict__ Q,
                                               const float* __restrict__ w,
                                               const int* __restrict__ Cmask, const int* __restrict__ Qmask,
                                               const float* __restrict__ c1, const float* __restrict__ q2,
                                               ushort* __restrict__ E, float* __restrict__ rsum,
                                               float* __restrict__ csum) {
    __shared__ float As[KC][TS + PAD];  // As[k][n]  (C*w3)
    __shared__ float Bs[KC][TS + PAD];  // Bs[k][m]  (Q)
    __shared__ float rowp[TS], colp[TS];
    const int bid = blockIdx.x;
    const int b   = bid >> 8;
    const int rem = bid & 255;
    const int n0  = (rem >> 3) << 6;
    const int m0  = (rem & 7) << 6;
    const int tid = threadIdx.x;
    const int tx = tid & 15, ty = tid >> 4;
    const int lr = tid >> 2, lk4 = (tid & 3) << 2;
    if (tid < TS) { rowp[tid] = 0.f; colp[tid] = 0.f; }
    float acc[4][4] = {};
    const float* Cb = C + ((size_t)(b * NN + n0)) * DD;
    const float* Qb = Q + ((size_t)(b * MM + m0)) * DD;
    const float* w3 = w + 2 * DD;
    for (int k0 = 0; k0 < DD; k0 += KC) {
        float4 cv = *(const float4*)(Cb + (size_t)lr * DD + k0 + lk4);
        float4 qv = *(const float4*)(Qb + (size_t)lr * DD + k0 + lk4);
        float4 wv = *(const float4*)(w3 + k0 + lk4);
        __syncthreads();
        As[lk4 + 0][lr] = cv.x * wv.x;
        As[lk4 + 1][lr] = cv.y * wv.y;
        As[lk4 + 2][lr] = cv.z * wv.z;
        As[lk4 + 3][lr] = cv.w * wv.w;
        Bs[lk4 + 0][lr] = qv.x;
        Bs[lk4 + 1][lr] = qv.y;
        Bs[lk4 + 2][lr] = qv.z;
        Bs[lk4 + 3][lr] = qv.w;
        __syncthreads();
#pragma unroll
        for (int kk = 0; kk < KC; ++kk) {
            const float4 av = *(const float4*)&As[kk][ty << 2];
            const float4 bv = *(const float4*)&Bs[kk][tx << 2];
            const float a_[4] = {av.x, av.y, av.z, av.w};
            const float b_[4] = {bv.x, bv.y, bv.z, bv.w};
#pragma unroll
            for (int i = 0; i < 4; ++i)
#pragma unroll
                for (int j = 0; j < 4; ++j) acc[i][j] += a_[i] * b_[j];
        }
    }
    const int gn = b * NN + n0;
    const int gm = b * MM + m0;
    float c1v[4], q2v[4]; int cmv[4], qmv[4];
#pragma unroll
    for (int i = 0; i < 4; ++i) { c1v[i] = c1[gn + (ty << 2) + i]; cmv[i] = Cmask[gn + (ty << 2) + i]; }
#pragma unroll
    for (int j = 0; j < 4; ++j) { q2v[j] = q2[gm + (tx << 2) + j]; qmv[j] = Qmask[gm + (tx << 2) + j]; }
    float rp[4] = {0, 0, 0, 0}, cp[4] = {0, 0, 0, 0};
#pragma unroll
    for (int i = 0; i < 4; ++i) {
        ushort4 ev;
        unsigned short* ep = &ev.x;
#pragma unroll
        for (int j = 0; j < 4; ++j) {
            float e = __expf(acc[i][j] + c1v[i] + q2v[j]);
            unsigned short eb = f2bf(e);
            float eq = bf2f(eb);
            ep[j] = eb;
            rp[i] += qmv[j] ? 0.f : eq;
            cp[j] += cmv[i] ? 0.f : eq;
        }
        *(ushort4*)&E[((size_t)(gn + (ty << 2) + i)) * MM + m0 + (tx << 2)] = ev;
    }
#pragma unroll
    for (int i = 0; i < 4; ++i) atomicAdd(&rowp[(ty << 2) + i], rp[i]);
#pragma unroll
    for (int j = 0; j < 4; ++j) atomicAdd(&colp[(tx << 2) + j], cp[j]);
    __syncthreads();
    if (tid < TS) atomicAdd(&rsum[gn + tid], rowp[tid]);
    else if (tid < 2 * TS) atomicAdd(&csum[gm + tid - TS], colp[tid - TS]);
}

// K3: T[b,m,d] = bf16( sum_n (Cmask[n]?0:E[n,m]) * C[b,n,d] / csum[b,m] )
__global__ __launch_bounds__(256) void k_T(const ushort* __restrict__ E, const float* __restrict__ C,
                                           const int* __restrict__ Cmask, const float* __restrict__ csum,
                                           ushort* __restrict__ T) {
    __shared__ float Ws[KC][TS + PAD];  // Ws[k(n)][m]
    __shared__ float Cs[KC][TS + PAD];  // Cs[k(n)][d]
    const int bid = blockIdx.x;
    const int b   = bid >> 6;
    const int rem = bid & 63;
    const int m0  = (rem >> 3) << 6;
    const int d0  = (rem & 7) << 6;
    const int tid = threadIdx.x;
    const int tx = tid & 15, ty = tid >> 4;
    const int kk = tid >> 4, c4 = (tid & 15) << 2;
    float acc[4][4] = {};
    for (int n0 = 0; n0 < NN; n0 += KC) {
        const int n = n0 + kk;
        ushort4 ev = *(const ushort4*)&E[((size_t)(b * NN + n)) * MM + m0 + c4];
        float4  cv = *(const float4*)(C + ((size_t)(b * NN + n)) * DD + d0 + c4);
        const float z = Cmask[b * NN + n] ? 0.f : 1.f;
        __syncthreads();
        *(float4*)&Ws[kk][c4] = make_float4(bf2f(ev.x) * z, bf2f(ev.y) * z, bf2f(ev.z) * z, bf2f(ev.w) * z);
        *(float4*)&Cs[kk][c4] = cv;
        __syncthreads();
#pragma unroll
        for (int k2 = 0; k2 < KC; ++k2) {
            const float4 av = *(const float4*)&Ws[k2][ty << 2];
            const float4 bv = *(const float4*)&Cs[k2][tx << 2];
            const float a_[4] = {av.x, av.y, av.z, av.w};
            const float b_[4] = {bv.x, bv.y, bv.z, bv.w};
#pragma unroll
            for (int i = 0; i < 4; ++i)
#pragma unroll
                for (int j = 0; j < 4; ++j) acc[i][j] += a_[i] * b_[j];
        }
    }
#pragma unroll
    for (int i = 0; i < 4; ++i) {
        float inv = 1.f / csum[b * MM + m0 + (ty << 2) + i];
        ushort4 ov;
        ov.x = f2bf(acc[i][0] * inv); ov.y = f2bf(acc[i][1] * inv);
        ov.z = f2bf(acc[i][2] * inv); ov.w = f2bf(acc[i][3] * inv);
        *(ushort4*)&T[((size_t)(b * MM + m0 + (ty << 2) + i)) * DD + d0 + (tx << 2)] = ov;
    }
}

// K4: A[b,n,d] = sum_m s1*Q[b,m,d]; Bout[b,n,d] = sum_m s1*T[b,m,d]; s1 = (Qmask?0:E)/rsum
// Outputs are FP32 (reference returns float32).
__global__ __launch_bounds__(256) void k_AB(const ushort* __restrict__ E, const float* __restrict__ Q,
                                            const ushort* __restrict__ T, const int* __restrict__ Qmask,
                                            const float* __restrict__ rsum,
                                            float* __restrict__ outA, float* __restrict__ outB) {
    __shared__ float Es[KC][TS + PAD];  // Es[k(m)][n]
    __shared__ float Qs[KC][TS + PAD];  // Qs[k(m)][d]
    __shared__ float Ts[KC][TS + PAD];  // Ts[k(m)][d]
    const int bid = blockIdx.x;
    const int b   = bid >> 8;
    const int rem = bid & 255;
    const int n0  = (rem >> 3) << 6;
    const int d0  = (rem & 7) << 6;
    const int tid = threadIdx.x;
    const int tx = tid & 15, ty = tid >> 4;
    const int lr = tid >> 2, lk4 = (tid & 3) << 2;  // E loader
    const int kk = tid >> 4, c4 = (tid & 15) << 2;  // Q/T loader
    float accA[4][4] = {}, accB[4][4] = {};
    for (int mq = 0; mq < MM; mq += KC) {
        ushort4 ev = *(const ushort4*)&E[((size_t)(b * NN + n0 + lr)) * MM + mq + lk4];
        float zq[4];
#pragma unroll
        for (int c = 0; c < 4; ++c) zq[c] = Qmask[b * MM + mq + lk4 + c] ? 0.f : 1.f;
        float4  qv = *(const float4*)(Q + ((size_t)(b * MM + mq + kk)) * DD + d0 + c4);
        ushort4 tv = *(const ushort4*)&T[((size_t)(b * MM + mq + kk)) * DD + d0 + c4];
        __syncthreads();
        Es[lk4 + 0][lr] = bf2f(ev.x) * zq[0];
        Es[lk4 + 1][lr] = bf2f(ev.y) * zq[1];
        Es[lk4 + 2][lr] = bf2f(ev.z) * zq[2];
        Es[lk4 + 3][lr] = bf2f(ev.w) * zq[3];
        *(float4*)&Qs[kk][c4] = qv;
        *(float4*)&Ts[kk][c4] = make_float4(bf2f(tv.x), bf2f(tv.y), bf2f(tv.z), bf2f(tv.w));
        __syncthreads();
#pragma unroll
        for (int k2 = 0; k2 < KC; ++k2) {
            const float4 av  = *(const float4*)&Es[k2][ty << 2];
            const float4 qv4 = *(const float4*)&Qs[k2][tx << 2];
            const float4 tv4 = *(const float4*)&Ts[k2][tx << 2];
            const float a_[4] = {av.x, av.y, av.z, av.w};
            const float q_[4] = {qv4.x, qv4.y, qv4.z, qv4.w};
            const float t_[4] = {tv4.x, tv4.y, tv4.z, tv4.w};
#pragma unroll
            for (int i = 0; i < 4; ++i)
#pragma unroll
                for (int j = 0; j < 4; ++j) {
                    accA[i][j] += a_[i] * q_[j];
                    accB[i][j] += a_[i] * t_[j];
                }
        }
    }
#pragma unroll
    for (int i = 0; i < 4; ++i) {
        float inv = 1.f / rsum[b * NN + n0 + (ty << 2) + i];
        size_t orow = ((size_t)(b * NN + n0 + (ty << 2) + i)) * DD + d0 + (tx << 2);
        float4 oa = make_float4(accA[i][0] * inv, accA[i][1] * inv, accA[i][2] * inv, accA[i][3] * inv);
        float4 ob = make_float4(accB[i][0] * inv, accB[i][1] * inv, accB[i][2] * inv, accB[i][3] * inv);
        *(float4*)&outA[orow] = oa;
        *(float4*)&outB[orow] = ob;
    }
}

extern "C" void kernel_launch(void* const* d_in, const int* in_sizes, int n_in,
                              void* d_out, int out_size, void* d_ws, size_t ws_size,
                              hipStream_t stream) {
    const float* C = (const float*)d_in[0];
    const float* Q = (const float*)d_in[1];
    const int* Cmask = (const int*)d_in[2];
    const int* Qmask = (const int*)d_in[3];
    const float* w  = (const float*)d_in[4];

    const size_t BNM = (size_t)BB * NN * MM;   // 33.5M (E, bf16)
    const size_t BMD = (size_t)BB * MM * DD;   // 8.4M  (T, bf16)
    const size_t BN  = (size_t)BB * NN;
    const size_t BM  = (size_t)BB * MM;

    ushort* E = (ushort*)d_ws;
    ushort* T = E + BNM;
    float* fbase = (float*)(T + BMD);          // byte offset 83,886,080 — 16B aligned
    float* c1   = fbase;
    float* q2   = c1 + BN;
    float* rsum = q2 + BM;
    float* csum = rsum + BN;

    hipMemsetAsync(rsum, 0, (BN + BM) * sizeof(float), stream);

    k_dots<<<(int)((BN + BM) / 4), 256, 0, stream>>>(C, Q, w, c1, q2);
    k_sgemm<<<BB * (NN / TS) * (MM / TS), 256, 0, stream>>>(C, Q, w, Cmask, Qmask, c1, q2, E, rsum, csum);
    k_T<<<BB * (MM / TS) * (DD / TS), 256, 0, stream>>>(E, C, Cmask, csum, T);
    k_AB<<<BB * (NN / TS) * (DD / TS), 256, 0, stream>>>(E, Q, T, Qmask, rsum,
                                                         (float*)d_out, (float*)d_out + (size_t)BB * NN * DD);
}